// Round 10
// baseline (116.144 us; speedup 1.0000x reference)
//
#include <hip/hip_runtime.h>
#include <hip/hip_bf16.h>

#define N_ROWS 32768
#define K_DIM 512
#define OUT_DIM 512
#define N_TYPES 8
#define BMR 128             // rows per block
#define NBR 264             // max 128-row blocks after per-type padding to 128
#define BK 64
#define NT (K_DIM / BK)     // 8 K-steps

typedef __attribute__((ext_vector_type(8))) short bf16x8;
typedef __attribute__((ext_vector_type(4))) float f32x4;

__device__ inline ushort f2bf(float f) {
    __hip_bfloat16 h = __float2bfloat16(f);
    return *reinterpret_cast<ushort*>(&h);
}

__device__ inline void gload_lds16(const void* g, void* l) {
    __builtin_amdgcn_global_load_lds(
        (const __attribute__((address_space(1))) void*)g,
        (__attribute__((address_space(3))) void*)l, 16, 0, 0);
}

// meta layout (ints): [0..7] counts, [8..15] padded bases, [16] padded total,
//                     [20..27] cursors
__global__ void k_init(int* meta) {
    if (threadIdx.x < 32) meta[threadIdx.x] = 0;
}

__global__ void k_hist(const int* __restrict__ x_type, int* meta) {
    __shared__ int cnt[N_TYPES];
    if (threadIdx.x < N_TYPES) cnt[threadIdx.x] = 0;
    __syncthreads();
    int i = blockIdx.x * 256 + threadIdx.x;
    atomicAdd(&cnt[x_type[i]], 1);
    __syncthreads();
    if (threadIdx.x < N_TYPES && cnt[threadIdx.x] > 0)
        atomicAdd(&meta[threadIdx.x], cnt[threadIdx.x]);
}

__global__ void k_scan(int* meta) {
    if (threadIdx.x == 0) {
        int s = 0;
        for (int t = 0; t < N_TYPES; ++t) {
            meta[8 + t]  = s;      // padded base
            meta[20 + t] = s;      // cursor
            s += (meta[t] + BMR - 1) & ~(BMR - 1);   // pad each type to 128
        }
        meta[16] = s;              // padded total
    }
}

// per-block LDS hist -> reserve range with 8 global atomics -> scatter
// (row_ids pre-filled with -1; pad slots stay -1)
__global__ void k_fill(const int* __restrict__ x_type, int* meta, int* __restrict__ row_ids) {
    __shared__ int lcnt[N_TYPES];
    __shared__ int lbase[N_TYPES];
    if (threadIdx.x < N_TYPES) lcnt[threadIdx.x] = 0;
    __syncthreads();
    int i = blockIdx.x * 256 + threadIdx.x;
    int t = x_type[i];
    int lpos = atomicAdd(&lcnt[t], 1);
    __syncthreads();
    if (threadIdx.x < N_TYPES)
        lbase[threadIdx.x] = (lcnt[threadIdx.x] > 0)
            ? atomicAdd(&meta[20 + threadIdx.x], lcnt[threadIdx.x]) : 0;
    __syncthreads();
    row_ids[lbase[t] + lpos] = i;
}

// W[t][k][c] fp32 -> Wt[t][c][k] bf16   (64x64 tiles through LDS)
__global__ void k_wt(const float* __restrict__ W, ushort* __restrict__ Wt) {
    __shared__ float tile[64][65];
    int t = blockIdx.x, kb = blockIdx.y, cb = blockIdx.z;
    const float* src = W + (size_t)t * K_DIM * OUT_DIM + (size_t)kb * 64 * OUT_DIM + cb * 64;
    #pragma unroll
    for (int j = 0; j < 16; ++j) {
        int idx = threadIdx.x + j * 256;
        int r = idx >> 6, c = idx & 63;
        tile[r][c] = src[(size_t)r * OUT_DIM + c];
    }
    __syncthreads();
    ushort* dst = Wt + (size_t)t * OUT_DIM * K_DIM + (size_t)(cb * 64) * K_DIM + kb * 64;
    #pragma unroll
    for (int j = 0; j < 16; ++j) {
        int idx = threadIdx.x + j * 256;
        int cc = idx >> 6, kk = idx & 63;
        dst[(size_t)cc * K_DIM + kk] = f2bf(tile[kk][cc]);
    }
}

// m97 structure: 128x128 tile, 4 waves (each 64x64 out, acc[4][4]), BK=64,
// single-buffered LDS (2 barriers/step), 32 MFMA per wave per step.
// LDS rows are 128 B; granule involution g ^= (id&7) -> conflict-free
// (proven 0 conflicts, rounds 6/8).  A: fused fp32->bf16 reg-stage +
// swizzled ds_write.  B: global_load_lds, inverse perm on SOURCE (rule #21).
__global__ __launch_bounds__(256) void k_gemm9(
    const float* __restrict__ x, const ushort* __restrict__ Wt,
    const int* __restrict__ meta, const int* __restrict__ row_ids,
    float* __restrict__ out) {

    __shared__ ushort As[BMR * BK];   // 16384 B, [row][64k], 128 B/row
    __shared__ ushort Bs[128 * BK];   // 16384 B, [col][64k]
    __shared__ int rids[BMR];

    int b = blockIdx.x;               // row-blocks fastest -> x L3-resident
    int r0 = b * BMR;
    if (r0 >= meta[16]) return;
    int type = 0;
    #pragma unroll
    for (int t = 0; t < N_TYPES; ++t)
        if (r0 >= meta[8 + t]) type = t;

    int tid = threadIdx.x;
    int wave = tid >> 6, lane = tid & 63;

    if (tid < BMR) rids[tid] = row_ids[r0 + tid];
    __syncthreads();

    int c0 = blockIdx.y * 128;
    const ushort* Wtt = Wt + (size_t)type * OUT_DIM * K_DIM + (size_t)c0 * K_DIM;

    // ---- A staging role: 2 threads/row, 32 elems (4 granules) each ----
    int sa_row  = tid >> 1;
    int sa_half = tid & 1;
    int sa_rid  = rids[sa_row];
    const float* sa_src = x + (size_t)max(sa_rid, 0) * K_DIM + sa_half * 32;

    // ---- B staging role: chunk = 8 cols x 128 B (1 KB); lane -> (col, pos);
    //      source granule = pos ^ (col&7)  (involution on SOURCE) ----
    int sb_col = lane >> 3;          // col within chunk (0..7)
    int sb_p   = lane & 7;           // dest granule position
    int sb_srcg = sb_p ^ sb_col;     // (col&7) == sb_col since chunk*8 is mult of 8

    int wrb = (wave >> 1) * 64;      // wave row base (0/64)
    int wcb = (wave & 1) * 64;       // wave col base (0/64)
    int lrow = lane & 15;
    int g16  = lane >> 4;            // k-granule within 32-k half (0..3)

    f32x4 acc[4][4] = {};

    #pragma unroll 2
    for (int t8 = 0; t8 < NT; ++t8) {
        int kk = t8 * BK;
        // ---- stage B: 4 chunks/wave (16 chunks = 128 cols) ----
        #pragma unroll
        for (int j = 0; j < 4; ++j) {
            int chunk = wave * 4 + j;
            int col = chunk * 8 + sb_col;
            gload_lds16(Wtt + (size_t)col * K_DIM + kk + sb_srcg * 8,
                        (char*)Bs + chunk * 1024);
        }
        // ---- stage A: 32 fp32 -> 32 bf16, 4 swizzled ds_write_b128 ----
        {
            float4 v[8];
            #pragma unroll
            for (int q = 0; q < 8; ++q)
                v[q] = (sa_rid >= 0)
                    ? *reinterpret_cast<const float4*>(sa_src + kk + q * 4)
                    : float4{0.f, 0.f, 0.f, 0.f};
            #pragma unroll
            for (int q = 0; q < 4; ++q) {
                ushort tmp[8] = {
                    f2bf(v[q*2].x),   f2bf(v[q*2].y),   f2bf(v[q*2].z),   f2bf(v[q*2].w),
                    f2bf(v[q*2+1].x), f2bf(v[q*2+1].y), f2bf(v[q*2+1].z), f2bf(v[q*2+1].w) };
                int p = sa_half * 4 + q;
                int byte = sa_row * 128 + ((p ^ (sa_row & 7)) * 16);
                *reinterpret_cast<uint4*>((char*)As + byte) =
                    *reinterpret_cast<const uint4*>(tmp);
            }
        }
        __syncthreads();

        // ---- compute: 2 k-halves x 16 MFMA ----
        #pragma unroll
        for (int s = 0; s < 2; ++s) {
            int g = s * 4 + g16;
            bf16x8 af[4], bfr[4];
            #pragma unroll
            for (int mi = 0; mi < 4; ++mi) {
                int row = wrb + mi * 16 + lrow;
                int byte = row * 128 + ((g ^ (row & 7)) * 16);
                af[mi] = *reinterpret_cast<const bf16x8*>((const char*)As + byte);
            }
            #pragma unroll
            for (int ni = 0; ni < 4; ++ni) {
                int col = wcb + ni * 16 + lrow;
                int byte = col * 128 + ((g ^ (col & 7)) * 16);
                bfr[ni] = *reinterpret_cast<const bf16x8*>((const char*)Bs + byte);
            }
            #pragma unroll
            for (int mi = 0; mi < 4; ++mi)
                #pragma unroll
                for (int ni = 0; ni < 4; ++ni)
                    acc[mi][ni] = __builtin_amdgcn_mfma_f32_16x16x32_bf16(
                        af[mi], bfr[ni], acc[mi][ni], 0, 0, 0);
        }
        __syncthreads();
    }

    // epilogue: D row = (lane>>4)*4 + rr, col = lane&15
    int rgrp = g16 * 4;
    #pragma unroll
    for (int mi = 0; mi < 4; ++mi) {
        #pragma unroll
        for (int rr = 0; rr < 4; ++rr) {
            int lr = wrb + mi * 16 + rgrp + rr;
            int gr = rids[lr];
            if (gr >= 0) {
                float* dst = out + (size_t)gr * OUT_DIM + c0 + wcb;
                #pragma unroll
                for (int ni = 0; ni < 4; ++ni)
                    dst[ni * 16 + lrow] = acc[mi][ni][rr];
            }
        }
    }
}

extern "C" void kernel_launch(void* const* d_in, const int* in_sizes, int n_in,
                              void* d_out, int out_size, void* d_ws, size_t ws_size,
                              hipStream_t stream) {
    const float* x      = (const float*)d_in[0];
    const int*   x_type = (const int*)d_in[1];
    const float* W      = (const float*)d_in[2];
    float* out          = (float*)d_out;

    char* ws = (char*)d_ws;
    size_t off_rids = 256;
    size_t off_wt   = off_rids + sizeof(int) * (NBR * BMR);
    int* meta    = (int*)ws;
    int* row_ids = (int*)(ws + off_rids);
    ushort* Wt   = (ushort*)(ws + off_wt);                  // 4 MB bf16

    k_init<<<1, 64, 0, stream>>>(meta);
    k_hist<<<N_ROWS / 256, 256, 0, stream>>>(x_type, meta);
    k_scan<<<1, 64, 0, stream>>>(meta);
    hipMemsetAsync(row_ids, 0xFF, sizeof(int) * (NBR * BMR), stream);
    k_fill<<<N_ROWS / 256, 256, 0, stream>>>(x_type, meta, row_ids);

    dim3 wgrid(N_TYPES, K_DIM / 64, OUT_DIM / 64);
    k_wt<<<wgrid, 256, 0, stream>>>(W, Wt);

    // row-blocks fastest: the 4 column passes over x (64 MB, L3-fits)
    // come a full pass apart -> L3-absorbed re-reads
    dim3 ggrid(NBR, OUT_DIM / 128);
    k_gemm9<<<ggrid, 256, 0, stream>>>(x, Wt, meta, row_ids, out);
}